// Round 6
// baseline (430.701 us; speedup 1.0000x reference)
//
#include <hip/hip_runtime.h>

// Problem constants (fixed by reference):
#define NB    32
#define CCH   256
#define HW    1024
#define NPIX  (NB*HW)     // 32768 pixels per input
#define DDICT 1024

#define EMB_ELEMS  ((size_t)NB*CCH*HW)      // 8388608
#define SEC_ELEMS  (2*EMB_ELEMS + NPIX)     // 16809984

// MFMA GEMM tiling
#define TPX  256           // pixels per block (8 waves x 32 pixels)
#define TD   128           // dicts per tile
#define NDT  (DDICT/TD)    // 8 d-tiles (all processed by each block)
#define BK   32            // K per chunk (one 16x16x32 MFMA)
#define NKC  (CCH/BK)      // 8 chunks
#define NPH  (NDT*NKC)     // 64 staging phases

#define TAU  0.125f        // near-tie threshold; split error ~6e-3 << TAU/2

typedef __attribute__((ext_vector_type(8))) short bf16x8;   // 8 bf16 = 4 VGPR
typedef __attribute__((ext_vector_type(4))) float f32x4;

// RNE round to bf16; returns bf16 bits, rest = exact residual.
__device__ inline ushort split_rne(float f, float& rest) {
    uint u = __float_as_uint(f);
    uint r = u + 0x7FFFu + ((u >> 16) & 1u);
    rest = f - __uint_as_float(r & 0xFFFF0000u);
    return (ushort)(r >> 16);
}

__device__ inline ushort rne_bf16(float f) {
    uint u = __float_as_uint(f);
    return (ushort)((u + 0x7FFFu + ((u >> 16) & 1u)) >> 16);
}

// async 16B global->LDS (linear dest: wave-uniform base + lane*16)
__device__ inline void gll16(const void* g, void* l) {
    __builtin_amdgcn_global_load_lds(
        (const __attribute__((address_space(1))) uint*)g,
        (__attribute__((address_space(3))) uint*)l,
        16, 0, 0);
}

// nontemporal 16B store via clang vector type (HIP float4 is a class -> invalid)
__device__ inline void nts16(float* p, float a, float b, float c, float d) {
    f32x4 v = {a, b, c, d};
    __builtin_nontemporal_store(v, (f32x4*)p);
}

// ---------------- Stage 0a: dictionary norms (+ zero rescue counters) --------
// UNCHANGED arithmetic — rescue + epilogue depend on bit-identical norms.
__global__ void dict_norms_kernel(const float* __restrict__ dict,
                                  float* __restrict__ norms,
                                  int* __restrict__ cnts) {
    if (blockIdx.x == 0 && threadIdx.x < 2) cnts[threadIdx.x] = 0;
    int d = blockIdx.x * blockDim.x + threadIdx.x;
    if (d < DDICT) {
        const float4* row = (const float4*)(dict + (size_t)d * CCH);
        float s = 0.f;
#pragma unroll 8
        for (int i = 0; i < CCH / 4; ++i) {
            float4 v = row[i];
            s += v.x * v.x + v.y * v.y + v.z * v.z + v.w * v.w;
        }
        norms[d] = s;
    }
}

// ---------------- Stage 0b: 2-way bf16 split of dictionary, PRE-TILED --------
// dHs/dMs: per (dt,kc) an 8KB chunk that IS the LDS image (swizzle baked in):
// elem = dd*32 + slot*8 + e, slot=(oct+(dd>>1))&3. vq_mfma stages it with
// linear global_load_lds. dictT = fp32 transpose for the rescue.
__global__ void dict_split_kernel(const float* __restrict__ dict,
                                  ushort* __restrict__ dHs,
                                  ushort* __restrict__ dMs,
                                  float* __restrict__ dictT) {
    int d = blockIdx.x;
    int lane = threadIdx.x;   // 0..63
    float4 f = ((const float4*)(dict + (size_t)d * CCH))[lane];
    float v[4] = {f.x, f.y, f.z, f.w};
    ushort h[4], m[4];
#pragma unroll
    for (int i = 0; i < 4; ++i) {
        float r1;
        h[i] = split_rne(v[i], r1);
        m[i] = rne_bf16(r1);
    }
    int c0 = lane * 4;                        // 4 consecutive channels, one octet
    int kc = c0 >> 5, oct = (c0 >> 3) & 3, e0 = c0 & 7;
    int dt = d >> 7, dd = d & 127;
    int slot = (oct + (dd >> 1)) & 3;
    size_t base = ((size_t)(dt * NKC + kc)) * 4096 + dd * 32 + slot * 8 + e0;
    *(ushort4*)(dHs + base) = make_ushort4(h[0], h[1], h[2], h[3]);
    *(ushort4*)(dMs + base) = make_ushort4(m[0], m[1], m[2], m[3]);
#pragma unroll
    for (int j = 0; j < 4; ++j)
        dictT[(size_t)(c0 + j) * DDICT + d] = v[j];
}

// ---------------- Stage 1: fused all-dict MFMA + top-2 + idx + emb writes ----
// grid (NPIX/256, 2 inputs) = 256 blocks = 1/CU, 512 threads = 8 waves; wave
// wv owns pixels [wv*32,+32) — per-wave math identical to round 4. Changes vs
// round 4 (targeting the B-re-read pacer):
//  * TPX 256: per-block B read is the same 2 MB but block count halves ->
//    total B volume 1 GB -> 512 MB.
//  * nontemporal loads for x prologue + nontemporal stores for emb/emb_pt:
//    keeps the streaming 221 MB out of L2 so the 2 MB dH/dM planes stay
//    L2-resident and staging runs at L2 rate, not L3.
//  * BK=32 double-buffered phases (Bs 2x16 KB), full-phase staging lead:
//      phase p: s_waitcnt vmcnt(0) [stage(p), issued one phase ago]
//               s_barrier ; stage(p+1) -> buf (p+1)&1 ; setprio(1) MFMA (0)
//    WAR-safe: buf (p+1)&1 last read in phase p-1; every wave's p-1 ds_reads
//    completed (operands consumed by issued MFMAs) before it entered
//    barrier(p). Accumulation order per acc element: kc ascending, same
//    3-product sequence -> bit-identical selection vs rounds 2-4.
__global__ __launch_bounds__(512, 1)
void vq_mfma_kernel(const float* __restrict__ x0,
                    const float* __restrict__ x1,
                    const ushort* __restrict__ dHs,
                    const ushort* __restrict__ dMs,
                    const float* __restrict__ norms,
                    const float* __restrict__ dict,
                    float* __restrict__ out,
                    int* __restrict__ cnts,
                    int* __restrict__ lists) {
    __shared__ ushort Bs[2][2][4096];   // [buf][plane][8KB] 32 KB
    __shared__ float nrm_s[DDICT];      // 4 KB (exact copy of norms)
    __shared__ int   idx_s[TPX];        // 1 KB

    const int t    = threadIdx.x;       // 0..511
    const int lane = t & 63;
    const int wv   = t >> 6;            // 0..7
    const int lx   = lane & 15;         // MFMA row/col index
    const int q    = lane >> 4;         // k-octet
    const int m0w  = wv * 32;           // wave pixel offset
    const int z    = blockIdx.y;

    const int g0  = blockIdx.x * TPX;
    const int n   = g0 / HW;
    const int hw0 = g0 % HW;            // tile stays within one n (256 | 1024)

    const float* x = z ? x1 : x0;
    float* out_base = out + (size_t)z * SEC_ELEMS;
    float* out_idx  = out_base + 2 * EMB_ELEMS;
    int* cnt  = cnts + z;
    int* list = lists + (size_t)z * NPIX;

    // norms -> LDS (bitwise copy; keeps the K-loop free of compiler VMEM)
    *(float2*)(nrm_s + t * 2) = *(const float2*)(norms + t * 2);

    // ---- A: direct coalesced fp32 reads of x (nontemporal) + 2-way split
    const float* xbase = x + (size_t)n * CCH * HW + hw0 + m0w + lx;
    bf16x8 Ah[8][2], Am[8][2];
#pragma unroll
    for (int kc = 0; kc < NKC; ++kc) {
        float a_f[2][8];
#pragma unroll
        for (int mi = 0; mi < 2; ++mi)
#pragma unroll
            for (int j = 0; j < 8; ++j)
                a_f[mi][j] = __builtin_nontemporal_load(
                    xbase + (size_t)(kc * BK + q * 8 + j) * HW + mi * 16);
#pragma unroll
        for (int mi = 0; mi < 2; ++mi)
#pragma unroll
            for (int j = 0; j < 8; ++j) {
                float r1;
                ushort h = split_rne(a_f[mi][j], r1);
                Ah[kc][mi][j] = (short)h;
                Am[kc][mi][j] = (short)rne_bf16(r1);
            }
    }

    // stage phase p (8KB x 2 planes = 16 KB): 2 gll16 per thread
    auto stage = [&](int p, int b) {
#pragma unroll
        for (int plane = 0; plane < 2; ++plane) {
            const ushort* sp = (plane ? dMs : dHs) + (size_t)p * 4096;
            gll16(sp + t * 8, &Bs[b][plane][wv * 512]);
        }
    };

    __syncthreads();          // nrm_s visible; x-loads drained by their uses
    stage(0, 0);

    // running top-2 per owned pixel-row
    float b1r[2][4], b2r[2][4]; int i1r[2][4];
#pragma unroll
    for (int mi = 0; mi < 2; ++mi)
#pragma unroll
        for (int r = 0; r < 4; ++r) {
            b1r[mi][r] = 3.0e38f; b2r[mi][r] = 3.0e38f; i1r[mi][r] = 0;
        }

    for (int dt = 0; dt < NDT; ++dt) {
        f32x4 acc[2][8] = {};            // reset per tile (same as round 4)
#pragma unroll
        for (int kc = 0; kc < NKC; ++kc) {
            const int p = dt * 8 + kc;
            asm volatile("s_waitcnt vmcnt(0)" ::: "memory");  // stage(p) done
            __builtin_amdgcn_s_barrier();
            if (p + 1 < NPH) stage(p + 1, (p + 1) & 1);       // full-phase lead

            const ushort* bb = &Bs[p & 1][0][0];
            __builtin_amdgcn_s_setprio(1);
#pragma unroll
            for (int ni = 0; ni < 8; ++ni) {
                int nn   = ni * 16 + lx;
                int slot = (q + (nn >> 1)) & 3;
                int off  = nn * 32 + slot * 8;
                bf16x8 Bh = *(const bf16x8*)(bb + off);
                bf16x8 Bm = *(const bf16x8*)(bb + 4096 + off);
#pragma unroll
                for (int mi = 0; mi < 2; ++mi) {
                    f32x4 c = acc[mi][ni];
                    c = __builtin_amdgcn_mfma_f32_16x16x32_bf16(Ah[kc][mi], Bh, c, 0, 0, 0);
                    c = __builtin_amdgcn_mfma_f32_16x16x32_bf16(Ah[kc][mi], Bm, c, 0, 0, 0);
                    c = __builtin_amdgcn_mfma_f32_16x16x32_bf16(Am[kc][mi], Bh, c, 0, 0, 0);
                    acc[mi][ni] = c;
                }
            }
            __builtin_amdgcn_s_setprio(0);
        }

        // ---- per-tile epilogue: top-2 within tile, then ascending strict-<
        //      merge — bit-identical to round 4 (nrm_s is a bitwise norms copy).
        const int d0 = dt * TD;
        float nrm[8];
#pragma unroll
        for (int ni = 0; ni < 8; ++ni) nrm[ni] = nrm_s[d0 + ni * 16 + lx];

#pragma unroll
        for (int mi = 0; mi < 2; ++mi)
#pragma unroll
            for (int r = 0; r < 4; ++r) {
                float c1 = 3.0e38f, c2 = 3.0e38f; int ci = 0;
#pragma unroll
                for (int ni = 0; ni < 8; ++ni) {    // ascending dict within lane
                    float dist = fmaf(-2.f, acc[mi][ni][r], nrm[ni]);
                    if (dist < c1)      { c2 = c1; c1 = dist; ci = ni * 16 + lx; }
                    else if (dist < c2) { c2 = dist; }
                }
#pragma unroll
                for (int off = 1; off < 16; off <<= 1) { // 16-lane, idx tie-break
                    float o1 = __shfl_xor(c1, off);
                    int   oi = __shfl_xor(ci, off);
                    float o2 = __shfl_xor(c2, off);
                    if (o1 < c1 || (o1 == c1 && oi < ci)) {
                        c2 = fminf(c1, o2); c1 = o1; ci = oi;
                    } else {
                        c2 = fminf(c2, o1);
                    }
                }
                if (c1 < b1r[mi][r]) {
                    b2r[mi][r] = fminf(b1r[mi][r], c2);
                    b1r[mi][r] = c1;
                    i1r[mi][r] = d0 + ci;
                } else {
                    b2r[mi][r] = fminf(b2r[mi][r], c1);
                }
            }
    }

    // ---- final: idx + rescue flags, then fused dict-gather emb writes
#pragma unroll
    for (int mi = 0; mi < 2; ++mi)
#pragma unroll
        for (int r = 0; r < 4; ++r) {
            if (lx == 0) {
                int loc = m0w + mi * 16 + q * 4 + r;      // C-row = quad*4 + reg
                int g = g0 + loc;
                idx_s[loc] = i1r[mi][r];
                out_idx[g] = (float)i1r[mi][r];
                if (b2r[mi][r] - b1r[mi][r] < TAU) {
                    int slot = atomicAdd(cnt, 1);
                    list[slot] = g;
                }
            }
        }
    __syncthreads();

    // gather-transpose-write for this block's 256 pixels (dict L2-resident);
    // nontemporal stores: pure streaming output, keep it out of L2.
    const int pg = t & 63;    // 64 groups of 4 pixels
    const int cg = t >> 6;    // 8 channel-groups of 32 channels
    const int hwp = hw0 + pg * 4;
    const float* r0 = dict + (size_t)idx_s[pg * 4 + 0] * CCH;
    const float* r1 = dict + (size_t)idx_s[pg * 4 + 1] * CCH;
    const float* r2 = dict + (size_t)idx_s[pg * 4 + 2] * CCH;
    const float* r3 = dict + (size_t)idx_s[pg * 4 + 3] * CCH;
    float* oe = out_base;
    float* op = out_base + EMB_ELEMS;
    const size_t obase = (size_t)n * CCH * HW + hwp;

#pragma unroll
    for (int cq = 0; cq < 8; ++cq) {
        int c = cg * 32 + cq * 4;
        float4 q0 = *(const float4*)(r0 + c);
        float4 q1 = *(const float4*)(r1 + c);
        float4 q2 = *(const float4*)(r2 + c);
        float4 q3 = *(const float4*)(r3 + c);
        nts16(oe + obase + (size_t)(c + 0) * HW, q0.x, q1.x, q2.x, q3.x);
        nts16(op + obase + (size_t)(c + 0) * HW, q0.x, q1.x, q2.x, q3.x);
        nts16(oe + obase + (size_t)(c + 1) * HW, q0.y, q1.y, q2.y, q3.y);
        nts16(op + obase + (size_t)(c + 1) * HW, q0.y, q1.y, q2.y, q3.y);
        nts16(oe + obase + (size_t)(c + 2) * HW, q0.z, q1.z, q2.z, q3.z);
        nts16(op + obase + (size_t)(c + 2) * HW, q0.z, q1.z, q2.z, q3.z);
        nts16(oe + obase + (size_t)(c + 3) * HW, q0.w, q1.w, q2.w, q3.w);
        nts16(op + obase + (size_t)(c + 3) * HW, q0.w, q1.w, q2.w, q3.w);
    }
}

// ---------------- Stage 3: exact-fp32 rescue of near-tie pixels --------------
// UNCHANGED (bit-identical arithmetic; coalesced dictT reads).
__global__ __launch_bounds__(256)
void vq_rescue_kernel(const float* __restrict__ x0,
                      const float* __restrict__ x1,
                      const float* __restrict__ dictT,
                      const float* __restrict__ dict,
                      const float* __restrict__ norms,
                      const int* __restrict__ cnts,
                      const int* __restrict__ lists,
                      float* __restrict__ out) {
    __shared__ float xr[CCH];
    __shared__ float rd_s[4];
    __shared__ int   ri_s[4];
    __shared__ int   bi_s;
    const int z = blockIdx.z;
    const float* x = z ? x1 : x0;
    const int* list = lists + (size_t)z * NPIX;
    float* out_emb    = out + (size_t)z * SEC_ELEMS;
    float* out_emb_pt = out_emb + EMB_ELEMS;
    float* out_idx    = out_emb + 2 * EMB_ELEMS;
    const int t    = threadIdx.x;
    const int lane = t & 63;
    const int wv   = t >> 6;
    const int total = cnts[z];

    for (int w = blockIdx.x; w < total; w += gridDim.x) {
        const int g  = list[w];
        const int n  = g / HW;
        const int hw = g % HW;
        xr[t] = x[(size_t)n * CCH * HW + (size_t)t * HW + hw];
        __syncthreads();

        float bd = 3.0e38f; int bi = 0;
#pragma unroll
        for (int dd = 0; dd < 4; ++dd) {          // dicts {t, 256+t, 512+t, 768+t}
            int d = dd * 256 + t;                 // ascending within thread
            float dot = 0.f;
#pragma unroll 8
            for (int k = 0; k < CCH; ++k)
                dot = fmaf(xr[k], dictT[(size_t)k * DDICT + d], dot);
            float dist = fmaf(-2.f, dot, norms[d]);
            if (dist < bd) { bd = dist; bi = d; }
        }
#pragma unroll
        for (int off = 1; off < 64; off <<= 1) {  // wave lexicographic min
            float od = __shfl_xor(bd, off);
            int   oi = __shfl_xor(bi, off);
            if (od < bd || (od == bd && oi < bi)) { bd = od; bi = oi; }
        }
        if (lane == 0) { rd_s[wv] = bd; ri_s[wv] = bi; }
        __syncthreads();
        if (t == 0) {
            float fb = rd_s[0]; int fi = ri_s[0];
#pragma unroll
            for (int q2 = 1; q2 < 4; ++q2)
                if (rd_s[q2] < fb || (rd_s[q2] == fb && ri_s[q2] < fi)) {
                    fb = rd_s[q2]; fi = ri_s[q2];
                }
            bi_s = fi;
            out_idx[g] = (float)fi;
        }
        __syncthreads();
        float v = dict[(size_t)bi_s * CCH + t];
        size_t o = (size_t)n * CCH * HW + (size_t)t * HW + hw;
        out_emb[o]    = v;
        out_emb_pt[o] = v;
        __syncthreads();   // xr reused next iteration
    }
}

extern "C" void kernel_launch(void* const* d_in, const int* in_sizes, int n_in,
                              void* d_out, int out_size, void* d_ws, size_t ws_size,
                              hipStream_t stream) {
    const float* x0   = (const float*)d_in[0];
    const float* x1   = (const float*)d_in[1];
    const float* dict = (const float*)d_in[2];
    float* out = (float*)d_out;

    // ws layout: norms 4K | dHs 512K | dMs 512K | dictT 1M | lists 2x128K | cnts 8
    float*  norms = (float*)d_ws;
    ushort* dHs   = (ushort*)(norms + DDICT);
    ushort* dMs   = dHs + (size_t)DDICT * CCH;
    float*  dictT = (float*)(dMs + (size_t)DDICT * CCH);
    int*    lists = (int*)(dictT + (size_t)DDICT * CCH);   // [2][NPIX]
    int*    cnts  = lists + 2 * NPIX;

    dict_norms_kernel<<<dim3(DDICT / 256), dim3(256), 0, stream>>>(dict, norms, cnts);
    dict_split_kernel<<<dim3(DDICT), dim3(64), 0, stream>>>(dict, dHs, dMs, dictT);

    vq_mfma_kernel<<<dim3(NPIX / TPX, 2), dim3(512), 0, stream>>>(
        x0, x1, dHs, dMs, norms, dict, out, cnts, lists);

    vq_rescue_kernel<<<dim3(1024, 1, 2), dim3(256), 0, stream>>>(
        x0, x1, dictT, dict, norms, cnts, lists, out);
}

// Round 7
// 421.046 us; speedup vs baseline: 1.0229x; 1.0229x over previous
//
#include <hip/hip_runtime.h>

// Problem constants (fixed by reference):
#define NB    32
#define CCH   256
#define HW    1024
#define NPIX  (NB*HW)     // 32768 pixels per input
#define DDICT 1024

#define EMB_ELEMS  ((size_t)NB*CCH*HW)      // 8388608
#define SEC_ELEMS  (2*EMB_ELEMS + NPIX)     // 16809984

// MFMA GEMM tiling
#define TPX  256           // pixels per block (8 waves x 32 pixels)
#define TD   128           // dicts per tile
#define NDT  (DDICT/TD)    // 8 d-tiles (all processed by each block)
#define BK   32            // K per chunk (one 16x16x32 MFMA)
#define NKC  (CCH/BK)      // 8 chunks
#define NPH  (NDT*NKC)     // 64 staging phases

// Near-tie threshold. Worst-case 3-product split error on dist <= ~5e-3
// (256 terms x ~3*2^-18 dropped products, x2); 0.05 keeps ~10x margin while
// cutting flag count ~2.5x vs 0.125 (rescue cost is linear in flags).
#define TAU  0.05f

#define RPX  16            // rescue: pixels batched per dictT sweep

typedef __attribute__((ext_vector_type(8))) short bf16x8;   // 8 bf16 = 4 VGPR
typedef __attribute__((ext_vector_type(4))) float f32x4;

// RNE round to bf16; returns bf16 bits, rest = exact residual.
__device__ inline ushort split_rne(float f, float& rest) {
    uint u = __float_as_uint(f);
    uint r = u + 0x7FFFu + ((u >> 16) & 1u);
    rest = f - __uint_as_float(r & 0xFFFF0000u);
    return (ushort)(r >> 16);
}

__device__ inline ushort rne_bf16(float f) {
    uint u = __float_as_uint(f);
    return (ushort)((u + 0x7FFFu + ((u >> 16) & 1u)) >> 16);
}

// async 16B global->LDS (linear dest: wave-uniform base + lane*16)
__device__ inline void gll16(const void* g, void* l) {
    __builtin_amdgcn_global_load_lds(
        (const __attribute__((address_space(1))) uint*)g,
        (__attribute__((address_space(3))) uint*)l,
        16, 0, 0);
}

// nontemporal 16B store via clang vector type (HIP float4 is a class -> invalid)
__device__ inline void nts16(float* p, float a, float b, float c, float d) {
    f32x4 v = {a, b, c, d};
    __builtin_nontemporal_store(v, (f32x4*)p);
}

// ---------------- Stage 0a: dictionary norms (+ zero rescue counters) --------
// UNCHANGED arithmetic — rescue + epilogue depend on bit-identical norms.
__global__ void dict_norms_kernel(const float* __restrict__ dict,
                                  float* __restrict__ norms,
                                  int* __restrict__ cnts) {
    if (blockIdx.x == 0 && threadIdx.x < 2) cnts[threadIdx.x] = 0;
    int d = blockIdx.x * blockDim.x + threadIdx.x;
    if (d < DDICT) {
        const float4* row = (const float4*)(dict + (size_t)d * CCH);
        float s = 0.f;
#pragma unroll 8
        for (int i = 0; i < CCH / 4; ++i) {
            float4 v = row[i];
            s += v.x * v.x + v.y * v.y + v.z * v.z + v.w * v.w;
        }
        norms[d] = s;
    }
}

// ---------------- Stage 0b: 2-way bf16 split of dictionary, PRE-TILED --------
// dHs/dMs: per (dt,kc) an 8KB chunk that IS the LDS image (swizzle baked in):
// elem = dd*32 + slot*8 + e, slot=(oct+(dd>>1))&3. vq_mfma stages it with
// linear global_load_lds. dictT = fp32 transpose for the rescue.
__global__ void dict_split_kernel(const float* __restrict__ dict,
                                  ushort* __restrict__ dHs,
                                  ushort* __restrict__ dMs,
                                  float* __restrict__ dictT) {
    int d = blockIdx.x;
    int lane = threadIdx.x;   // 0..63
    float4 f = ((const float4*)(dict + (size_t)d * CCH))[lane];
    float v[4] = {f.x, f.y, f.z, f.w};
    ushort h[4], m[4];
#pragma unroll
    for (int i = 0; i < 4; ++i) {
        float r1;
        h[i] = split_rne(v[i], r1);
        m[i] = rne_bf16(r1);
    }
    int c0 = lane * 4;                        // 4 consecutive channels, one octet
    int kc = c0 >> 5, oct = (c0 >> 3) & 3, e0 = c0 & 7;
    int dt = d >> 7, dd = d & 127;
    int slot = (oct + (dd >> 1)) & 3;
    size_t base = ((size_t)(dt * NKC + kc)) * 4096 + dd * 32 + slot * 8 + e0;
    *(ushort4*)(dHs + base) = make_ushort4(h[0], h[1], h[2], h[3]);
    *(ushort4*)(dMs + base) = make_ushort4(m[0], m[1], m[2], m[3]);
#pragma unroll
    for (int j = 0; j < 4; ++j)
        dictT[(size_t)(c0 + j) * DDICT + d] = v[j];
}

// ---------------- Stage 1: fused all-dict MFMA + top-2 + idx + emb writes ----
// Identical to round 6 EXCEPT: x prologue loads are plain (cached) again —
// rescue re-reads x, and R6's nt-loads cost ~35 us of tail. nt emb stores kept
// (pure streaming, never re-read).
__global__ __launch_bounds__(512, 1)
void vq_mfma_kernel(const float* __restrict__ x0,
                    const float* __restrict__ x1,
                    const ushort* __restrict__ dHs,
                    const ushort* __restrict__ dMs,
                    const float* __restrict__ norms,
                    const float* __restrict__ dict,
                    float* __restrict__ out,
                    int* __restrict__ cnts,
                    int* __restrict__ lists) {
    __shared__ ushort Bs[2][2][4096];   // [buf][plane][8KB] 32 KB
    __shared__ float nrm_s[DDICT];      // 4 KB (exact copy of norms)
    __shared__ int   idx_s[TPX];        // 1 KB

    const int t    = threadIdx.x;       // 0..511
    const int lane = t & 63;
    const int wv   = t >> 6;            // 0..7
    const int lx   = lane & 15;         // MFMA row/col index
    const int q    = lane >> 4;         // k-octet
    const int m0w  = wv * 32;           // wave pixel offset
    const int z    = blockIdx.y;

    const int g0  = blockIdx.x * TPX;
    const int n   = g0 / HW;
    const int hw0 = g0 % HW;            // tile stays within one n (256 | 1024)

    const float* x = z ? x1 : x0;
    float* out_base = out + (size_t)z * SEC_ELEMS;
    float* out_idx  = out_base + 2 * EMB_ELEMS;
    int* cnt  = cnts + z;
    int* list = lists + (size_t)z * NPIX;

    // norms -> LDS (bitwise copy; keeps the K-loop free of compiler VMEM)
    *(float2*)(nrm_s + t * 2) = *(const float2*)(norms + t * 2);

    // ---- A: direct coalesced fp32 reads of x + exact 2-way split, ONCE
    const float* xbase = x + (size_t)n * CCH * HW + hw0 + m0w + lx;
    bf16x8 Ah[8][2], Am[8][2];
#pragma unroll
    for (int kc = 0; kc < NKC; ++kc) {
        float a_f[2][8];
#pragma unroll
        for (int mi = 0; mi < 2; ++mi)
#pragma unroll
            for (int j = 0; j < 8; ++j)
                a_f[mi][j] = xbase[(size_t)(kc * BK + q * 8 + j) * HW + mi * 16];
#pragma unroll
        for (int mi = 0; mi < 2; ++mi)
#pragma unroll
            for (int j = 0; j < 8; ++j) {
                float r1;
                ushort h = split_rne(a_f[mi][j], r1);
                Ah[kc][mi][j] = (short)h;
                Am[kc][mi][j] = (short)rne_bf16(r1);
            }
    }

    // stage phase p (8KB x 2 planes = 16 KB): 2 gll16 per thread
    auto stage = [&](int p, int b) {
#pragma unroll
        for (int plane = 0; plane < 2; ++plane) {
            const ushort* sp = (plane ? dMs : dHs) + (size_t)p * 4096;
            gll16(sp + t * 8, &Bs[b][plane][wv * 512]);
        }
    };

    __syncthreads();          // nrm_s visible; x-loads drained by their uses
    stage(0, 0);

    // running top-2 per owned pixel-row
    float b1r[2][4], b2r[2][4]; int i1r[2][4];
#pragma unroll
    for (int mi = 0; mi < 2; ++mi)
#pragma unroll
        for (int r = 0; r < 4; ++r) {
            b1r[mi][r] = 3.0e38f; b2r[mi][r] = 3.0e38f; i1r[mi][r] = 0;
        }

    for (int dt = 0; dt < NDT; ++dt) {
        f32x4 acc[2][8] = {};            // reset per tile (same as round 4)
#pragma unroll
        for (int kc = 0; kc < NKC; ++kc) {
            const int p = dt * 8 + kc;
            asm volatile("s_waitcnt vmcnt(0)" ::: "memory");  // stage(p) done
            __builtin_amdgcn_s_barrier();
            if (p + 1 < NPH) stage(p + 1, (p + 1) & 1);       // full-phase lead

            const ushort* bb = &Bs[p & 1][0][0];
            __builtin_amdgcn_s_setprio(1);
#pragma unroll
            for (int ni = 0; ni < 8; ++ni) {
                int nn   = ni * 16 + lx;
                int slot = (q + (nn >> 1)) & 3;
                int off  = nn * 32 + slot * 8;
                bf16x8 Bh = *(const bf16x8*)(bb + off);
                bf16x8 Bm = *(const bf16x8*)(bb + 4096 + off);
#pragma unroll
                for (int mi = 0; mi < 2; ++mi) {
                    f32x4 c = acc[mi][ni];
                    c = __builtin_amdgcn_mfma_f32_16x16x32_bf16(Ah[kc][mi], Bh, c, 0, 0, 0);
                    c = __builtin_amdgcn_mfma_f32_16x16x32_bf16(Ah[kc][mi], Bm, c, 0, 0, 0);
                    c = __builtin_amdgcn_mfma_f32_16x16x32_bf16(Am[kc][mi], Bh, c, 0, 0, 0);
                    acc[mi][ni] = c;
                }
            }
            __builtin_amdgcn_s_setprio(0);
        }

        // ---- per-tile epilogue: top-2 within tile, then ascending strict-<
        //      merge — bit-identical to rounds 2-6.
        const int d0 = dt * TD;
        float nrm[8];
#pragma unroll
        for (int ni = 0; ni < 8; ++ni) nrm[ni] = nrm_s[d0 + ni * 16 + lx];

#pragma unroll
        for (int mi = 0; mi < 2; ++mi)
#pragma unroll
            for (int r = 0; r < 4; ++r) {
                float c1 = 3.0e38f, c2 = 3.0e38f; int ci = 0;
#pragma unroll
                for (int ni = 0; ni < 8; ++ni) {    // ascending dict within lane
                    float dist = fmaf(-2.f, acc[mi][ni][r], nrm[ni]);
                    if (dist < c1)      { c2 = c1; c1 = dist; ci = ni * 16 + lx; }
                    else if (dist < c2) { c2 = dist; }
                }
#pragma unroll
                for (int off = 1; off < 16; off <<= 1) { // 16-lane, idx tie-break
                    float o1 = __shfl_xor(c1, off);
                    int   oi = __shfl_xor(ci, off);
                    float o2 = __shfl_xor(c2, off);
                    if (o1 < c1 || (o1 == c1 && oi < ci)) {
                        c2 = fminf(c1, o2); c1 = o1; ci = oi;
                    } else {
                        c2 = fminf(c2, o1);
                    }
                }
                if (c1 < b1r[mi][r]) {
                    b2r[mi][r] = fminf(b1r[mi][r], c2);
                    b1r[mi][r] = c1;
                    i1r[mi][r] = d0 + ci;
                } else {
                    b2r[mi][r] = fminf(b2r[mi][r], c1);
                }
            }
    }

    // ---- final: idx + rescue flags, then fused dict-gather emb writes
#pragma unroll
    for (int mi = 0; mi < 2; ++mi)
#pragma unroll
        for (int r = 0; r < 4; ++r) {
            if (lx == 0) {
                int loc = m0w + mi * 16 + q * 4 + r;      // C-row = quad*4 + reg
                int g = g0 + loc;
                idx_s[loc] = i1r[mi][r];
                out_idx[g] = (float)i1r[mi][r];
                if (b2r[mi][r] - b1r[mi][r] < TAU) {
                    int slot = atomicAdd(cnt, 1);
                    list[slot] = g;
                }
            }
        }
    __syncthreads();

    // gather-transpose-write for this block's 256 pixels (dict L2-resident);
    // nontemporal stores: pure streaming output, keep it out of L2.
    const int pg = t & 63;    // 64 groups of 4 pixels
    const int cg = t >> 6;    // 8 channel-groups of 32 channels
    const int hwp = hw0 + pg * 4;
    const float* r0 = dict + (size_t)idx_s[pg * 4 + 0] * CCH;
    const float* r1 = dict + (size_t)idx_s[pg * 4 + 1] * CCH;
    const float* r2 = dict + (size_t)idx_s[pg * 4 + 2] * CCH;
    const float* r3 = dict + (size_t)idx_s[pg * 4 + 3] * CCH;
    float* oe = out_base;
    float* op = out_base + EMB_ELEMS;
    const size_t obase = (size_t)n * CCH * HW + hwp;

#pragma unroll
    for (int cq = 0; cq < 8; ++cq) {
        int c = cg * 32 + cq * 4;
        float4 q0 = *(const float4*)(r0 + c);
        float4 q1 = *(const float4*)(r1 + c);
        float4 q2 = *(const float4*)(r2 + c);
        float4 q3 = *(const float4*)(r3 + c);
        nts16(oe + obase + (size_t)(c + 0) * HW, q0.x, q1.x, q2.x, q3.x);
        nts16(op + obase + (size_t)(c + 0) * HW, q0.x, q1.x, q2.x, q3.x);
        nts16(oe + obase + (size_t)(c + 1) * HW, q0.y, q1.y, q2.y, q3.y);
        nts16(op + obase + (size_t)(c + 1) * HW, q0.y, q1.y, q2.y, q3.y);
        nts16(oe + obase + (size_t)(c + 2) * HW, q0.z, q1.z, q2.z, q3.z);
        nts16(op + obase + (size_t)(c + 2) * HW, q0.z, q1.z, q2.z, q3.z);
        nts16(oe + obase + (size_t)(c + 3) * HW, q0.w, q1.w, q2.w, q3.w);
        nts16(op + obase + (size_t)(c + 3) * HW, q0.w, q1.w, q2.w, q3.w);
    }
}

// ---------------- Stage 3: BATCHED exact-fp32 rescue of near-tie pixels ------
// The old rescue swept the full 1 MB dictT per flagged pixel (L2-BW-bound,
// ~29 ns/pixel aggregate -> ~170 us at ~6k flags). Now 16 pixels share one
// dictT sweep (16x less L2 traffic). Per-(pixel,dict) arithmetic is
// BIT-IDENTICAL to rounds 1-6: fmaf chain k-ascending into a private acc,
// dist = fmaf(-2,dot,norms[d]), per-thread dd-ascending update, same wave
// shfl_xor lexicographic reduce, same wv 0->3 final merge.
__global__ __launch_bounds__(256)
void vq_rescue_kernel(const float* __restrict__ x0,
                      const float* __restrict__ x1,
                      const float* __restrict__ dictT,
                      const float* __restrict__ dict,
                      const float* __restrict__ norms,
                      const int* __restrict__ cnts,
                      const int* __restrict__ lists,
                      float* __restrict__ out) {
    __shared__ float xr[CCH][RPX];      // 16 KB, k-major for b128 reads
    __shared__ float rd_s[4][RPX];
    __shared__ int   ri_s[4][RPX];
    __shared__ int   gi_s[RPX];
    __shared__ int   bi_s[RPX];
    const int z = blockIdx.y;
    const float* x = z ? x1 : x0;
    const int* list = lists + (size_t)z * NPIX;
    float* out_emb    = out + (size_t)z * SEC_ELEMS;
    float* out_emb_pt = out_emb + EMB_ELEMS;
    float* out_idx    = out_emb + 2 * EMB_ELEMS;
    const int t    = threadIdx.x;
    const int lane = t & 63;
    const int wv   = t >> 6;
    const int total = cnts[z];

    for (int w0 = blockIdx.x * RPX; w0 < total; w0 += gridDim.x * RPX) {
        const int np = min(RPX, total - w0);
        if (t < RPX) gi_s[t] = list[w0 + ((t < np) ? t : (np - 1))];
        __syncthreads();

        // stage x for the batch: 16 threads per pixel x 16 channels each
        {
            const int p  = t >> 4;
            const int j0 = (t & 15) * 16;
            const int g  = gi_s[p];
            const int n  = g / HW, hw = g % HW;
            const float* xb = x + (size_t)n * CCH * HW + hw;
#pragma unroll
            for (int j = 0; j < 16; ++j)
                xr[j0 + j][p] = xb[(size_t)(j0 + j) * HW];
        }
        __syncthreads();

        // thread t owns dicts {t, 256+t, 512+t, 768+t}; acc[dd][p] private
        float acc[4][RPX] = {};
        for (int k = 0; k < CCH; ++k) {
            float xp[RPX];
#pragma unroll
            for (int p4 = 0; p4 < RPX / 4; ++p4) {
                f32x4 v = *(const f32x4*)&xr[k][p4 * 4];
#pragma unroll
                for (int j = 0; j < 4; ++j) xp[p4 * 4 + j] = v[j];
            }
#pragma unroll
            for (int dd = 0; dd < 4; ++dd) {
                float v = dictT[(size_t)k * DDICT + dd * 256 + t];
#pragma unroll
                for (int p = 0; p < RPX; ++p)
                    acc[dd][p] = fmaf(xp[p], v, acc[dd][p]);
            }
        }

        // per-pixel selection: identical comparison/reduction order as before
#pragma unroll
        for (int p = 0; p < RPX; ++p) {
            float bd = 3.0e38f; int bi = 0;
#pragma unroll
            for (int dd = 0; dd < 4; ++dd) {      // ascending within thread
                int d = dd * 256 + t;
                float dist = fmaf(-2.f, acc[dd][p], norms[d]);
                if (dist < bd) { bd = dist; bi = d; }
            }
#pragma unroll
            for (int off = 1; off < 64; off <<= 1) {  // wave lexicographic min
                float od = __shfl_xor(bd, off);
                int   oi = __shfl_xor(bi, off);
                if (od < bd || (od == bd && oi < bi)) { bd = od; bi = oi; }
            }
            if (lane == 0) { rd_s[wv][p] = bd; ri_s[wv][p] = bi; }
        }
        __syncthreads();
        if (t < RPX) {
            const int p = t;
            float fb = rd_s[0][p]; int fi = ri_s[0][p];
#pragma unroll
            for (int q2 = 1; q2 < 4; ++q2)
                if (rd_s[q2][p] < fb || (rd_s[q2][p] == fb && ri_s[q2][p] < fi)) {
                    fb = rd_s[q2][p]; fi = ri_s[q2][p];
                }
            bi_s[p] = fi;
            if (p < np) out_idx[gi_s[p]] = (float)fi;
        }
        __syncthreads();

        // overwrite emb rows for the batch: 16 threads per pixel
        {
            const int p  = t >> 4;
            const int j0 = (t & 15) * 16;
            if (p < np) {
                const int g = gi_s[p];
                const int n = g / HW, hw = g % HW;
                const float* dr = dict + (size_t)bi_s[p] * CCH;
                const size_t ob = (size_t)n * CCH * HW + hw;
#pragma unroll
                for (int j = 0; j < 16; ++j) {
                    float v = dr[j0 + j];
                    out_emb[ob + (size_t)(j0 + j) * HW]    = v;
                    out_emb_pt[ob + (size_t)(j0 + j) * HW] = v;
                }
            }
        }
        __syncthreads();   // xr/gi_s reused next iteration
    }
}

extern "C" void kernel_launch(void* const* d_in, const int* in_sizes, int n_in,
                              void* d_out, int out_size, void* d_ws, size_t ws_size,
                              hipStream_t stream) {
    const float* x0   = (const float*)d_in[0];
    const float* x1   = (const float*)d_in[1];
    const float* dict = (const float*)d_in[2];
    float* out = (float*)d_out;

    // ws layout: norms 4K | dHs 512K | dMs 512K | dictT 1M | lists 2x128K | cnts 8
    float*  norms = (float*)d_ws;
    ushort* dHs   = (ushort*)(norms + DDICT);
    ushort* dMs   = dHs + (size_t)DDICT * CCH;
    float*  dictT = (float*)(dMs + (size_t)DDICT * CCH);
    int*    lists = (int*)(dictT + (size_t)DDICT * CCH);   // [2][NPIX]
    int*    cnts  = lists + 2 * NPIX;

    dict_norms_kernel<<<dim3(DDICT / 256), dim3(256), 0, stream>>>(dict, norms, cnts);
    dict_split_kernel<<<dim3(DDICT), dim3(64), 0, stream>>>(dict, dHs, dMs, dictT);

    vq_mfma_kernel<<<dim3(NPIX / TPX, 2), dim3(512), 0, stream>>>(
        x0, x1, dHs, dMs, norms, dict, out, cnts, lists);

    vq_rescue_kernel<<<dim3(512, 2), dim3(256), 0, stream>>>(
        x0, x1, dictT, dict, norms, cnts, lists, out);
}

// Round 8
// 393.575 us; speedup vs baseline: 1.0943x; 1.0698x over previous
//
#include <hip/hip_runtime.h>

// Problem constants (fixed by reference):
#define NB    32
#define CCH   256
#define HW    1024
#define NPIX  (NB*HW)     // 32768 pixels per input
#define DDICT 1024

#define EMB_ELEMS  ((size_t)NB*CCH*HW)      // 8388608
#define SEC_ELEMS  (2*EMB_ELEMS + NPIX)     // 16809984

// MFMA GEMM tiling
#define TPX  128           // pixels per block (8 waves x 16 pixels)
#define TD   128           // dicts per tile
#define NDT  (DDICT/TD)    // 8 d-tiles (all processed by each block)
#define BK   32            // K per chunk (one 16x16x32 MFMA)
#define NKC  (CCH/BK)      // 8 chunks
#define NPH  (NDT*NKC)     // 64 staging phases

// Near-tie threshold. Worst-case 3-product split error on dist <= ~5e-3;
// 0.05 keeps ~10x margin (rescue cost linear in flag count).
#define TAU  0.05f

#define RPX  16            // rescue: pixels batched per dictT sweep

typedef __attribute__((ext_vector_type(8))) short bf16x8;   // 8 bf16 = 4 VGPR
typedef __attribute__((ext_vector_type(4))) float f32x4;

// RNE round to bf16; returns bf16 bits, rest = exact residual.
__device__ inline ushort split_rne(float f, float& rest) {
    uint u = __float_as_uint(f);
    uint r = u + 0x7FFFu + ((u >> 16) & 1u);
    rest = f - __uint_as_float(r & 0xFFFF0000u);
    return (ushort)(r >> 16);
}

__device__ inline ushort rne_bf16(float f) {
    uint u = __float_as_uint(f);
    return (ushort)((u + 0x7FFFu + ((u >> 16) & 1u)) >> 16);
}

// async 16B global->LDS (linear dest: wave-uniform base + lane*16)
__device__ inline void gll16(const void* g, void* l) {
    __builtin_amdgcn_global_load_lds(
        (const __attribute__((address_space(1))) uint*)g,
        (__attribute__((address_space(3))) uint*)l,
        16, 0, 0);
}

// ---------------- Stage 0a: dictionary norms (+ zero rescue counters) --------
// UNCHANGED arithmetic — rescue + epilogue depend on bit-identical norms.
__global__ void dict_norms_kernel(const float* __restrict__ dict,
                                  float* __restrict__ norms,
                                  int* __restrict__ cnts) {
    if (blockIdx.x == 0 && threadIdx.x < 2) cnts[threadIdx.x] = 0;
    int d = blockIdx.x * blockDim.x + threadIdx.x;
    if (d < DDICT) {
        const float4* row = (const float4*)(dict + (size_t)d * CCH);
        float s = 0.f;
#pragma unroll 8
        for (int i = 0; i < CCH / 4; ++i) {
            float4 v = row[i];
            s += v.x * v.x + v.y * v.y + v.z * v.z + v.w * v.w;
        }
        norms[d] = s;
    }
}

// ---------------- Stage 0b: 2-way bf16 split of dictionary, PRE-TILED --------
// dHs/dMs: per (dt,kc) an 8KB chunk that IS the LDS image (swizzle baked in):
// elem = dd*32 + slot*8 + e, slot=(oct+(dd>>1))&3. vq_mfma stages it with
// linear global_load_lds. dictT = fp32 transpose for the rescue.
__global__ void dict_split_kernel(const float* __restrict__ dict,
                                  ushort* __restrict__ dHs,
                                  ushort* __restrict__ dMs,
                                  float* __restrict__ dictT) {
    int d = blockIdx.x;
    int lane = threadIdx.x;   // 0..63
    float4 f = ((const float4*)(dict + (size_t)d * CCH))[lane];
    float v[4] = {f.x, f.y, f.z, f.w};
    ushort h[4], m[4];
#pragma unroll
    for (int i = 0; i < 4; ++i) {
        float r1;
        h[i] = split_rne(v[i], r1);
        m[i] = rne_bf16(r1);
    }
    int c0 = lane * 4;                        // 4 consecutive channels, one octet
    int kc = c0 >> 5, oct = (c0 >> 3) & 3, e0 = c0 & 7;
    int dt = d >> 7, dd = d & 127;
    int slot = (oct + (dd >> 1)) & 3;
    size_t base = ((size_t)(dt * NKC + kc)) * 4096 + dd * 32 + slot * 8 + e0;
    *(ushort4*)(dHs + base) = make_ushort4(h[0], h[1], h[2], h[3]);
    *(ushort4*)(dMs + base) = make_ushort4(m[0], m[1], m[2], m[3]);
#pragma unroll
    for (int j = 0; j < 4; ++j)
        dictT[(size_t)(c0 + j) * DDICT + d] = v[j];
}

// ---------------- Stage 1: fused all-dict MFMA + top-2 + idx + emb writes ----
// OCCUPANCY EXPERIMENT (the one structural variable not yet varied): every
// prior round ran 2 waves/SIMD (8 waves/CU, 32 pixels/wave). Here each wave
// owns 16 pixels (mi dimension removed): 4096 waves total -> 16 waves/CU =
// 4/SIMD, forced by __launch_bounds__(512,4) (A-frags halve to 64 VGPR so
// 128-VGPR cap fits). Per-(pixel,dict) accumulation order, staging schedule
// (vmcnt(0)+barrier+full-phase-lead double-buffer), top-2 merge, TAU flags:
// all unchanged -> bit-identical outputs. All nt hints reverted (R4 semantics).
__global__ __launch_bounds__(512, 4)
void vq_mfma_kernel(const float* __restrict__ x0,
                    const float* __restrict__ x1,
                    const ushort* __restrict__ dHs,
                    const ushort* __restrict__ dMs,
                    const float* __restrict__ norms,
                    const float* __restrict__ dict,
                    float* __restrict__ out,
                    int* __restrict__ cnts,
                    int* __restrict__ lists) {
    __shared__ ushort Bs[2][2][4096];   // [buf][plane][8KB] 32 KB
    __shared__ float nrm_s[DDICT];      // 4 KB (exact copy of norms)
    __shared__ int   idx_s[TPX];        // 512 B

    const int t    = threadIdx.x;       // 0..511
    const int lane = t & 63;
    const int wv   = t >> 6;            // 0..7
    const int lx   = lane & 15;         // MFMA row/col index
    const int q    = lane >> 4;         // k-octet / C-row quad
    const int m0w  = wv * 16;           // wave pixel offset (16 pixels/wave)
    const int z    = blockIdx.y;

    const int g0  = blockIdx.x * TPX;
    const int n   = g0 / HW;
    const int hw0 = g0 % HW;            // tile stays within one n (128 | 1024)

    const float* x = z ? x1 : x0;
    float* out_base = out + (size_t)z * SEC_ELEMS;
    float* out_idx  = out_base + 2 * EMB_ELEMS;
    int* cnt  = cnts + z;
    int* list = lists + (size_t)z * NPIX;

    // norms -> LDS (bitwise copy; keeps the K-loop free of compiler VMEM)
    *(float2*)(nrm_s + t * 2) = *(const float2*)(norms + t * 2);

    // ---- A: direct coalesced fp32 reads of x + exact 2-way split, ONCE
    const float* xbase = x + (size_t)n * CCH * HW + hw0 + m0w + lx;
    bf16x8 Ah[8], Am[8];
#pragma unroll
    for (int kc = 0; kc < NKC; ++kc) {
        float a_f[8];
#pragma unroll
        for (int j = 0; j < 8; ++j)
            a_f[j] = xbase[(size_t)(kc * BK + q * 8 + j) * HW];
#pragma unroll
        for (int j = 0; j < 8; ++j) {
            float r1;
            ushort h = split_rne(a_f[j], r1);
            Ah[kc][j] = (short)h;
            Am[kc][j] = (short)rne_bf16(r1);
        }
    }

    // stage phase p (8KB x 2 planes = 16 KB): 2 gll16 per thread
    auto stage = [&](int p, int b) {
#pragma unroll
        for (int plane = 0; plane < 2; ++plane) {
            const ushort* sp = (plane ? dMs : dHs) + (size_t)p * 4096;
            gll16(sp + t * 8, &Bs[b][plane][wv * 512]);
        }
    };

    __syncthreads();          // nrm_s visible; x-loads drained by their uses
    stage(0, 0);

    // running top-2 per owned pixel-row (row = q*4 + r)
    float b1r[4], b2r[4]; int i1r[4];
#pragma unroll
    for (int r = 0; r < 4; ++r) {
        b1r[r] = 3.0e38f; b2r[r] = 3.0e38f; i1r[r] = 0;
    }

    for (int dt = 0; dt < NDT; ++dt) {
        f32x4 acc[8] = {};               // reset per tile (same as before)
#pragma unroll
        for (int kc = 0; kc < NKC; ++kc) {
            const int p = dt * 8 + kc;
            asm volatile("s_waitcnt vmcnt(0)" ::: "memory");  // stage(p) done
            __builtin_amdgcn_s_barrier();
            if (p + 1 < NPH) stage(p + 1, (p + 1) & 1);       // full-phase lead

            const ushort* bb = &Bs[p & 1][0][0];
            __builtin_amdgcn_s_setprio(1);
#pragma unroll
            for (int ni = 0; ni < 8; ++ni) {
                int nn   = ni * 16 + lx;
                int slot = (q + (nn >> 1)) & 3;
                int off  = nn * 32 + slot * 8;
                bf16x8 Bh = *(const bf16x8*)(bb + off);
                bf16x8 Bm = *(const bf16x8*)(bb + 4096 + off);
                f32x4 c = acc[ni];
                c = __builtin_amdgcn_mfma_f32_16x16x32_bf16(Ah[kc], Bh, c, 0, 0, 0);
                c = __builtin_amdgcn_mfma_f32_16x16x32_bf16(Ah[kc], Bm, c, 0, 0, 0);
                c = __builtin_amdgcn_mfma_f32_16x16x32_bf16(Am[kc], Bh, c, 0, 0, 0);
                acc[ni] = c;
            }
            __builtin_amdgcn_s_setprio(0);
        }

        // ---- per-tile epilogue: top-2 within tile, then ascending strict-<
        //      merge — comparison/reduction order identical to prior rounds.
        const int d0 = dt * TD;
        float nrm[8];
#pragma unroll
        for (int ni = 0; ni < 8; ++ni) nrm[ni] = nrm_s[d0 + ni * 16 + lx];

#pragma unroll
        for (int r = 0; r < 4; ++r) {
            float c1 = 3.0e38f, c2 = 3.0e38f; int ci = 0;
#pragma unroll
            for (int ni = 0; ni < 8; ++ni) {        // ascending dict within lane
                float dist = fmaf(-2.f, acc[ni][r], nrm[ni]);
                if (dist < c1)      { c2 = c1; c1 = dist; ci = ni * 16 + lx; }
                else if (dist < c2) { c2 = dist; }
            }
#pragma unroll
            for (int off = 1; off < 16; off <<= 1) {  // 16-lane, idx tie-break
                float o1 = __shfl_xor(c1, off);
                int   oi = __shfl_xor(ci, off);
                float o2 = __shfl_xor(c2, off);
                if (o1 < c1 || (o1 == c1 && oi < ci)) {
                    c2 = fminf(c1, o2); c1 = o1; ci = oi;
                } else {
                    c2 = fminf(c2, o1);
                }
            }
            if (c1 < b1r[r]) {
                b2r[r] = fminf(b1r[r], c2);
                b1r[r] = c1;
                i1r[r] = d0 + ci;
            } else {
                b2r[r] = fminf(b2r[r], c1);
            }
        }
    }

    // ---- final: idx + rescue flags, then fused dict-gather emb writes
#pragma unroll
    for (int r = 0; r < 4; ++r) {
        if (lx == 0) {
            int loc = m0w + q * 4 + r;                // C-row = quad*4 + reg
            int g = g0 + loc;
            idx_s[loc] = i1r[r];
            out_idx[g] = (float)i1r[r];
            if (b2r[r] - b1r[r] < TAU) {
                int slot = atomicAdd(cnt, 1);
                list[slot] = g;
            }
        }
    }
    __syncthreads();

    // gather-transpose-write for this block's 128 pixels (dict L2-resident)
    const int pg = t & 31;    // 32 groups of 4 pixels
    const int cg = t >> 5;    // 16 channel-groups of 16 channels
    const int hwp = hw0 + pg * 4;
    const float* r0 = dict + (size_t)idx_s[pg * 4 + 0] * CCH;
    const float* r1 = dict + (size_t)idx_s[pg * 4 + 1] * CCH;
    const float* r2 = dict + (size_t)idx_s[pg * 4 + 2] * CCH;
    const float* r3 = dict + (size_t)idx_s[pg * 4 + 3] * CCH;
    float* oe = out_base;
    float* op = out_base + EMB_ELEMS;
    const size_t obase = (size_t)n * CCH * HW + hwp;

#pragma unroll
    for (int cq = 0; cq < 4; ++cq) {
        int c = cg * 16 + cq * 4;
        float4 q0 = *(const float4*)(r0 + c);
        float4 q1 = *(const float4*)(r1 + c);
        float4 q2 = *(const float4*)(r2 + c);
        float4 q3 = *(const float4*)(r3 + c);
        float4 v0 = make_float4(q0.x, q1.x, q2.x, q3.x);
        float4 v1 = make_float4(q0.y, q1.y, q2.y, q3.y);
        float4 v2 = make_float4(q0.z, q1.z, q2.z, q3.z);
        float4 v3 = make_float4(q0.w, q1.w, q2.w, q3.w);
        *(float4*)(oe + obase + (size_t)(c + 0) * HW) = v0;
        *(float4*)(op + obase + (size_t)(c + 0) * HW) = v0;
        *(float4*)(oe + obase + (size_t)(c + 1) * HW) = v1;
        *(float4*)(op + obase + (size_t)(c + 1) * HW) = v1;
        *(float4*)(oe + obase + (size_t)(c + 2) * HW) = v2;
        *(float4*)(op + obase + (size_t)(c + 2) * HW) = v2;
        *(float4*)(oe + obase + (size_t)(c + 3) * HW) = v3;
        *(float4*)(op + obase + (size_t)(c + 3) * HW) = v3;
    }
}

// ---------------- Stage 3: BATCHED exact-fp32 rescue of near-tie pixels ------
// 16 pixels share one dictT sweep. Per-(pixel,dict) arithmetic BIT-IDENTICAL
// to all prior rounds: fmaf chain k-ascending, dist = fmaf(-2,dot,norms[d]),
// dd-ascending update, wave shfl_xor lexicographic reduce, wv 0->3 merge.
__global__ __launch_bounds__(256)
void vq_rescue_kernel(const float* __restrict__ x0,
                      const float* __restrict__ x1,
                      const float* __restrict__ dictT,
                      const float* __restrict__ dict,
                      const float* __restrict__ norms,
                      const int* __restrict__ cnts,
                      const int* __restrict__ lists,
                      float* __restrict__ out) {
    __shared__ float xr[CCH][RPX];      // 16 KB, k-major
    __shared__ float rd_s[4][RPX];
    __shared__ int   ri_s[4][RPX];
    __shared__ int   gi_s[RPX];
    __shared__ int   bi_s[RPX];
    const int z = blockIdx.y;
    const float* x = z ? x1 : x0;
    const int* list = lists + (size_t)z * NPIX;
    float* out_emb    = out + (size_t)z * SEC_ELEMS;
    float* out_emb_pt = out_emb + EMB_ELEMS;
    float* out_idx    = out_emb + 2 * EMB_ELEMS;
    const int t    = threadIdx.x;
    const int lane = t & 63;
    const int wv   = t >> 6;
    const int total = cnts[z];

    for (int w0 = blockIdx.x * RPX; w0 < total; w0 += gridDim.x * RPX) {
        const int np = min(RPX, total - w0);
        if (t < RPX) gi_s[t] = list[w0 + ((t < np) ? t : (np - 1))];
        __syncthreads();

        // stage x for the batch: 16 threads per pixel x 16 channels each
        {
            const int p  = t >> 4;
            const int j0 = (t & 15) * 16;
            const int g  = gi_s[p];
            const int n  = g / HW, hw = g % HW;
            const float* xb = x + (size_t)n * CCH * HW + hw;
#pragma unroll
            for (int j = 0; j < 16; ++j)
                xr[j0 + j][p] = xb[(size_t)(j0 + j) * HW];
        }
        __syncthreads();

        // thread t owns dicts {t, 256+t, 512+t, 768+t}; acc[dd][p] private
        float acc[4][RPX] = {};
        for (int k = 0; k < CCH; ++k) {
            float xp[RPX];
#pragma unroll
            for (int p4 = 0; p4 < RPX / 4; ++p4) {
                f32x4 v = *(const f32x4*)&xr[k][p4 * 4];
#pragma unroll
                for (int j = 0; j < 4; ++j) xp[p4 * 4 + j] = v[j];
            }
#pragma unroll
            for (int dd = 0; dd < 4; ++dd) {
                float v = dictT[(size_t)k * DDICT + dd * 256 + t];
#pragma unroll
                for (int p = 0; p < RPX; ++p)
                    acc[dd][p] = fmaf(xp[p], v, acc[dd][p]);
            }
        }

        // per-pixel selection: identical comparison/reduction order as before
#pragma unroll
        for (int p = 0; p < RPX; ++p) {
            float bd = 3.0e38f; int bi = 0;
#pragma unroll
            for (int dd = 0; dd < 4; ++dd) {      // ascending within thread
                int d = dd * 256 + t;
                float dist = fmaf(-2.f, acc[dd][p], norms[d]);
                if (dist < bd) { bd = dist; bi = d; }
            }
#pragma unroll
            for (int off = 1; off < 64; off <<= 1) {  // wave lexicographic min
                float od = __shfl_xor(bd, off);
                int   oi = __shfl_xor(bi, off);
                if (od < bd || (od == bd && oi < bi)) { bd = od; bi = oi; }
            }
            if (lane == 0) { rd_s[wv][p] = bd; ri_s[wv][p] = bi; }
        }
        __syncthreads();
        if (t < RPX) {
            const int p = t;
            float fb = rd_s[0][p]; int fi = ri_s[0][p];
#pragma unroll
            for (int q2 = 1; q2 < 4; ++q2)
                if (rd_s[q2][p] < fb || (rd_s[q2][p] == fb && ri_s[q2][p] < fi)) {
                    fb = rd_s[q2][p]; fi = ri_s[q2][p];
                }
            bi_s[p] = fi;
            if (p < np) out_idx[gi_s[p]] = (float)fi;
        }
        __syncthreads();

        // overwrite emb rows for the batch: 16 threads per pixel
        {
            const int p  = t >> 4;
            const int j0 = (t & 15) * 16;
            if (p < np) {
                const int g = gi_s[p];
                const int n = g / HW, hw = g % HW;
                const float* dr = dict + (size_t)bi_s[p] * CCH;
                const size_t ob = (size_t)n * CCH * HW + hw;
#pragma unroll
                for (int j = 0; j < 16; ++j) {
                    float v = dr[j0 + j];
                    out_emb[ob + (size_t)(j0 + j) * HW]    = v;
                    out_emb_pt[ob + (size_t)(j0 + j) * HW] = v;
                }
            }
        }
        __syncthreads();   // xr/gi_s reused next iteration
    }
}

extern "C" void kernel_launch(void* const* d_in, const int* in_sizes, int n_in,
                              void* d_out, int out_size, void* d_ws, size_t ws_size,
                              hipStream_t stream) {
    const float* x0   = (const float*)d_in[0];
    const float* x1   = (const float*)d_in[1];
    const float* dict = (const float*)d_in[2];
    float* out = (float*)d_out;

    // ws layout: norms 4K | dHs 512K | dMs 512K | dictT 1M | lists 2x128K | cnts 8
    float*  norms = (float*)d_ws;
    ushort* dHs   = (ushort*)(norms + DDICT);
    ushort* dMs   = dHs + (size_t)DDICT * CCH;
    float*  dictT = (float*)(dMs + (size_t)DDICT * CCH);
    int*    lists = (int*)(dictT + (size_t)DDICT * CCH);   // [2][NPIX]
    int*    cnts  = lists + 2 * NPIX;

    dict_norms_kernel<<<dim3(DDICT / 256), dim3(256), 0, stream>>>(dict, norms, cnts);
    dict_split_kernel<<<dim3(DDICT), dim3(64), 0, stream>>>(dict, dHs, dMs, dictT);

    vq_mfma_kernel<<<dim3(NPIX / TPX, 2), dim3(512), 0, stream>>>(
        x0, x1, dHs, dMs, norms, dict, out, cnts, lists);

    vq_rescue_kernel<<<dim3(512, 2), dim3(256), 0, stream>>>(
        x0, x1, dictT, dict, norms, cnts, lists, out);
}